// Round 14
// baseline (581.379 us; speedup 1.0000x reference)
//
#include <hip/hip_runtime.h>
#include <hip/hip_bf16.h>
#include <math.h>

// Problem constants
#define EE 200
#define RR 480
#define TT 8
#define NN 40000
#define BB 1024
#define KP 224          // K=200 padded to 32-multiple
#define GP 672          // gate-padded width: 3 x 224
#define GPR 704         // 11*64 row padding for 672-col MFMA tiles

typedef __attribute__((ext_vector_type(8))) short short8v;   // 8 bf16
typedef __attribute__((ext_vector_type(4))) float f32x4;

__device__ inline unsigned short f2bf(float x) {  // RNE fp32->bf16
    unsigned int u = __float_as_uint(x);
    unsigned int r = ((u >> 16) & 1u) + 0x7fffu;
    return (unsigned short)((u + r) >> 16);
}
__device__ inline float bf2f(unsigned short h) {
    return __uint_as_float(((unsigned int)h) << 16);
}
__device__ inline float sigm(float x) { return 1.0f / (1.0f + __expf(-x)); }
__device__ inline void split_store(unsigned short* hi, unsigned short* lo, size_t i, float v) {
    unsigned short h = f2bf(v);
    hi[i] = h;
    lo[i] = f2bf(v - bf2f(h));
}

// ---------------------------------------------------------------------------
struct PrepPtrs {
    unsigned short *W1h, *W1l, *W2h, *W2l, *Wabh, *Wabl, *Wh2h, *Wh2l;
    unsigned short *Walh, *Wall, *WTh, *WTl, *wgh, *wgl, *whg, *whl;
    float *bab, *bihp, *bhhp;
    unsigned short *mapSh, *mapSl, *wgiSh, *wgiSl, *hbufs;
    double* acc;
};

// One-shot prep: all weight hi/lo splits (padded), bias pads, arena zeroing.
__global__ __launch_bounds__(256) void prep_kernel(
    const float* __restrict__ W1, const float* __restrict__ W2,
    const float* __restrict__ Wa, const float* __restrict__ Wh1,
    const float* __restrict__ Wh2, const float* __restrict__ Wal,
    const float* __restrict__ bal, const float* __restrict__ wih,
    const float* __restrict__ whh, const float* __restrict__ ba,
    const float* __restrict__ bh1, const float* __restrict__ bih,
    const float* __restrict__ bhh, PrepPtrs p)
{
    const int gt = blockIdx.x * 256 + threadIdx.x;
    const int gs = gridDim.x * 256;

    for (int i = gt; i < 448 * 224; i += gs) {
        int r = i / 224, c = i - r * 224;
        split_store(p.W1h, p.W1l, i, (r < 400 && c < 200) ? W1[r * 200 + c] : 0.f);
        float vab = 0.f;
        if (c < 200) {
            if (r < 200) vab = Wa[r * 200 + c];
            else if (r >= 224 && r < 424) vab = Wh1[(r - 224) * 200 + c];
        }
        split_store(p.Wabh, p.Wabl, i, vab);
    }
    for (int i = gt; i < 256 * 416; i += gs) {
        int r = i / 416, c = i - r * 416;
        split_store(p.W2h, p.W2l, i, (r < 200 && c < 400) ? W2[r * 400 + c] : 0.f);
    }
    for (int i = gt; i < 256 * 224; i += gs) {
        int r = i / 224, c = i - r * 224;
        bool in = (r < 200 && c < 200);
        split_store(p.Wh2h, p.Wh2l, i, in ? Wh2[r * 200 + c] : 0.f);
        split_store(p.Walh, p.Wall, i, in ? Wal[r * 200 + c] : 0.f);
        float vt = in ? Wal[c * 200 + r] : ((r == 200 && c < 200) ? bal[c] : 0.f);
        split_store(p.WTh, p.WTl, i, vt);
    }
    for (int i = gt; i < 672 * 224; i += gs) {
        int rr = i / 224, c = i - rr * 224;
        int g = rr / 224, j = rr - g * 224;
        bool in = (j < 200 && c < 200);
        split_store(p.wgh, p.wgl, i, in ? wih[(size_t)(g * 200 + j) * 200 + c] : 0.f);
        split_store(p.whg, p.whl, i, in ? whh[(size_t)(g * 200 + j) * 200 + c] : 0.f);
    }
    for (int i = gt; i < 448; i += gs) {
        float v = 0.f;
        if (i < 200) v = ba[i];
        else if (i >= 224 && i < 424) v = bh1[i - 224];
        p.bab[i] = v;
    }
    for (int i = gt; i < GPR; i += gs) {
        int g = i / 224, j = i - g * 224;
        p.bihp[i] = (g < 3 && j < 200) ? bih[g * 200 + j] : 0.f;
    }
    for (int i = gt; i < GP; i += gs) {
        int g = i / 224, j = i - g * 224;
        p.bhhp[i] = (j < 200) ? bhh[g * 200 + j] : 0.f;
    }
    for (int i = gt; i < 512 * 224; i += gs) { p.mapSh[i] = 0; p.mapSl[i] = 0; }
    for (int i = gt; i < 704 * 480; i += gs) { p.wgiSh[i] = 0; p.wgiSl[i] = 0; }
    for (int i = gt; i < 4 * BB * KP; i += gs) p.hbufs[i] = 0;
    if (gt == 0) { p.acc[0] = 0.0; p.acc[1] = 0.0; }
}

// ---------------------------------------------------------------------------
// bf16x3 MFMA linear with on-the-fly A conversion (fp32 A, pre-split B).
template <int MODE, int OUT, int GATHER, int GATEPAD, int EGATHER>
__global__ __launch_bounds__(256) void mfma_flyA(
    const float* __restrict__ A, int lda, const int* __restrict__ gidx, int gsel,
    const unsigned short* __restrict__ Bhi, const unsigned short* __restrict__ Blo,
    const float* __restrict__ bias,
    float* __restrict__ Cf, unsigned short* __restrict__ Chi, unsigned short* __restrict__ Clo,
    int M, int N, int Ka, int Ks,
    const float* __restrict__ extra, int eld, float alpha, int obf)
{
    const int tid = threadIdx.x;
    const int wave = tid >> 6, lane = tid & 63;
    const int r16 = lane & 15, kq = lane >> 4;
    const int kbase = kq * 8;
    const int bm = blockIdx.y * 64 + wave * 16;
    const int bn = blockIdx.x * 64;

    int arow = bm + r16;
    const bool avalid = arow < M;
    if (GATHER) { if (avalid) arow = gidx[arow * 3 + gsel]; }
    const float* Ap = A + (size_t)arow * lda;

    f32x4 acc[4] = {{0,0,0,0},{0,0,0,0},{0,0,0,0},{0,0,0,0}};
    const int nk = Ks >> 5;

    for (int kk = 0; kk < nk; kk++) {
        const int k0 = kk * 32 + kbase;
        short8v a0, a1;
        #pragma unroll
        for (int e = 0; e < 8; e++) {
            float v = (avalid && (k0 + e) < Ka) ? Ap[k0 + e] : 0.f;
            unsigned short h = f2bf(v);
            a0[e] = (short)h;
            a1[e] = (short)f2bf(v - bf2f(h));
        }
        #pragma unroll
        for (int nf = 0; nf < 4; nf++) {
            const size_t boff = (size_t)(bn + nf * 16 + r16) * Ks + k0;
            short8v b0 = *(const short8v*)(Bhi + boff);
            short8v b1 = *(const short8v*)(Blo + boff);
            acc[nf] = __builtin_amdgcn_mfma_f32_16x16x32_bf16(a0, b1, acc[nf], 0, 0, 0);
            acc[nf] = __builtin_amdgcn_mfma_f32_16x16x32_bf16(a1, b0, acc[nf], 0, 0, 0);
            acc[nf] = __builtin_amdgcn_mfma_f32_16x16x32_bf16(a0, b0, acc[nf], 0, 0, 0);
        }
    }

    #pragma unroll
    for (int r = 0; r < 4; r++) {
        const int orow = bm + kq * 4 + r;
        if (orow >= M) continue;
        #pragma unroll
        for (int nf = 0; nf < 4; nf++) {
            const int col = bn + nf * 16 + r16;
            float v = acc[nf][r];
            if (OUT == 0) {
                if (col < N) {
                    if (bias) v += bias[col];
                    if (MODE == 1) {
                        float ex = EGATHER ? extra[(size_t)gidx[orow * 3 + gsel] * eld + col]
                                           : extra[(size_t)orow * eld + col];
                        v = alpha * v + ex;
                    } else if (MODE == 2) {
                        v = v * extra[(size_t)orow * eld + col];
                    }
                    Cf[(size_t)orow * N + col] = v;
                }
            } else if (OUT == 1) {
                if (col < obf) {
                    float w = 0.f;
                    if (col < N) { w = v; if (bias) w += bias[col]; }
                    Chi[(size_t)orow * obf + col] = f2bf(w);
                }
            } else if (OUT == 2) {
                if (col < N) {
                    int wr = GATEPAD ? (orow / 200) * 224 + orow % 200 : orow;
                    if (bias) v += bias[col];
                    split_store(Chi, Clo, (size_t)wr * obf + col, v);
                }
            } else if (OUT == 3) {
                if (col < N) {
                    if (bias) v += bias[col];
                    Cf[(size_t)orow * N + col] = v;
                    split_store(Chi, Clo, (size_t)orow * obf + col, v);
                }
            }
        }
    }
}

// ---------------------------------------------------------------------------
// bf16x1 MFMA linear: C = A_hi @ B_hi^T + bias (both already bf16).
__global__ __launch_bounds__(256) void mfma_linear1_kernel(
    const unsigned short* __restrict__ Ahi,
    const unsigned short* __restrict__ Bhi,
    const float* __restrict__ bias, float* __restrict__ C,
    int M, int N, int Ks)
{
    const int tid  = threadIdx.x;
    const int wave = tid >> 6;
    const int lane = tid & 63;
    const int r16   = lane & 15;
    const int khalf = lane >> 4;
    const int kbase = khalf * 8;
    const int bm = blockIdx.y * 64 + wave * 16;
    const int bn = blockIdx.x * 64;

    const unsigned short* ah = Ahi + (size_t)(bm + r16) * Ks + kbase;
    const unsigned short* bh = Bhi + (size_t)(bn + r16) * Ks + kbase;

    f32x4 acc[4] = {{0,0,0,0},{0,0,0,0},{0,0,0,0},{0,0,0,0}};

    for (int k0 = 0; k0 < Ks; k0 += 32) {
        short8v a0 = *(const short8v*)(ah + k0);
        #pragma unroll
        for (int nf = 0; nf < 4; nf++) {
            short8v b0 = *(const short8v*)(bh + (size_t)nf * 16 * Ks + k0);
            acc[nf] = __builtin_amdgcn_mfma_f32_16x16x32_bf16(a0, b0, acc[nf], 0, 0, 0);
        }
    }
    #pragma unroll
    for (int r = 0; r < 4; r++) {
        const int row = bm + khalf * 4 + r;
        #pragma unroll
        for (int nf = 0; nf < 4; nf++) {
            const int col = bn + nf * 16 + r16;
            if (col < N)
                C[(size_t)row * N + col] = acc[nf][r] + (bias ? bias[col] : 0.0f);
        }
    }
}

// ---------------------------------------------------------------------------
// One GRU step (fused gh-GEMM + combine), grid (13, 16) x 256.
template <int FIRST, int LAST>
__global__ __launch_bounds__(256) void gru_step_kernel(
    const unsigned short* __restrict__ Whi, const unsigned short* __restrict__ Wlo,
    const float* __restrict__ bhh_pad,
    const float* __restrict__ gi_t,
    const unsigned short* __restrict__ hin_hi, const unsigned short* __restrict__ hin_lo,
    unsigned short* __restrict__ hout_hi, unsigned short* __restrict__ hout_lo,
    float* __restrict__ h_fin)
{
    const int tid = threadIdx.x;
    const int wave = tid >> 6, lane = tid & 63;
    const int r16 = lane & 15, kq = lane >> 4;
    const int jf = blockIdx.x;
    const int brow = (blockIdx.y * 4 + wave) * 16;
    const int j = jf * 16 + r16;

    f32x4 ar = {0,0,0,0}, az = {0,0,0,0}, an = {0,0,0,0};
    if (!FIRST) {
        short8v ahi[7], alo[7];
        const unsigned short* hh = hin_hi + (size_t)(brow + r16) * KP + kq * 8;
        const unsigned short* hl = hin_lo + (size_t)(brow + r16) * KP + kq * 8;
        #pragma unroll
        for (int kk = 0; kk < 7; kk++) {
            ahi[kk] = *(const short8v*)(hh + kk * 32);
            alo[kk] = *(const short8v*)(hl + kk * 32);
        }
        #pragma unroll
        for (int kk = 0; kk < 7; kk++) {
            const size_t rowr = (size_t)(jf * 16 + r16) * KP + kk * 32 + kq * 8;
            const size_t rowz = rowr + (size_t)224 * KP;
            const size_t rown = rowr + (size_t)448 * KP;
            short8v brh = *(const short8v*)(Whi + rowr);
            short8v brl = *(const short8v*)(Wlo + rowr);
            short8v bzh = *(const short8v*)(Whi + rowz);
            short8v bzl = *(const short8v*)(Wlo + rowz);
            short8v bnh = *(const short8v*)(Whi + rown);
            short8v bnl = *(const short8v*)(Wlo + rown);
            ar = __builtin_amdgcn_mfma_f32_16x16x32_bf16(ahi[kk], brl, ar, 0, 0, 0);
            az = __builtin_amdgcn_mfma_f32_16x16x32_bf16(ahi[kk], bzl, az, 0, 0, 0);
            an = __builtin_amdgcn_mfma_f32_16x16x32_bf16(ahi[kk], bnl, an, 0, 0, 0);
            ar = __builtin_amdgcn_mfma_f32_16x16x32_bf16(alo[kk], brh, ar, 0, 0, 0);
            az = __builtin_amdgcn_mfma_f32_16x16x32_bf16(alo[kk], bzh, az, 0, 0, 0);
            an = __builtin_amdgcn_mfma_f32_16x16x32_bf16(alo[kk], bnh, an, 0, 0, 0);
            ar = __builtin_amdgcn_mfma_f32_16x16x32_bf16(ahi[kk], brh, ar, 0, 0, 0);
            az = __builtin_amdgcn_mfma_f32_16x16x32_bf16(ahi[kk], bzh, az, 0, 0, 0);
            an = __builtin_amdgcn_mfma_f32_16x16x32_bf16(ahi[kk], bnh, an, 0, 0, 0);
        }
    }

    const float br = bhh_pad[j], bz = bhh_pad[224 + j], bn_ = bhh_pad[448 + j];
    #pragma unroll
    for (int q = 0; q < 4; q++) {
        const int row = brow + kq * 4 + q;
        float gir = gi_t[(size_t)row * GP + j];
        float giz = gi_t[(size_t)row * GP + 224 + j];
        float gin = gi_t[(size_t)row * GP + 448 + j];
        float r_ = sigm(gir + ar[q] + br);
        float z_ = sigm(giz + az[q] + bz);
        float n_ = tanhf(gin + r_ * (an[q] + bn_));
        float hold = 0.0f;
        if (!FIRST)
            hold = bf2f(hin_hi[(size_t)row * KP + j]) + bf2f(hin_lo[(size_t)row * KP + j]);
        float hnew = (1.0f - z_) * n_ + z_ * hold;
        if (j < EE) {
            unsigned short nh = f2bf(hnew);
            hout_hi[(size_t)row * KP + j] = nh;
            hout_lo[(size_t)row * KP + j] = f2bf(hnew - bf2f(nh));
            if (LAST) h_fin[(size_t)row * EE + j] = hnew;
        }
    }
}

// ---------------------------------------------------------------------------
// gru_hidden2 = gru_cell(x = map[rel], h = pred), fused; + match-loss partial.
__global__ __launch_bounds__(256) void gru2_fused_kernel(
    const unsigned short* __restrict__ Wihi, const unsigned short* __restrict__ Wilo,
    const unsigned short* __restrict__ Whhi, const unsigned short* __restrict__ Whlo,
    const float* __restrict__ bih_pad, const float* __restrict__ bhh_pad,
    const int* __restrict__ triples, const float* __restrict__ map,
    const float* __restrict__ hp, const float* __restrict__ hfin,
    float* __restrict__ ghid2, double* __restrict__ accMatch)
{
    __shared__ float red[256];
    const int tid = threadIdx.x;
    const int wave = tid >> 6, lane = tid & 63;
    const int r16 = lane & 15, kq = lane >> 4;
    const int jf = blockIdx.x;
    const int brow = (blockIdx.y * 4 + wave) * 16;
    const int j = jf * 16 + r16;

    f32x4 ir = {0,0,0,0}, iz = {0,0,0,0}, in_ = {0,0,0,0};
    f32x4 hr = {0,0,0,0}, hz = {0,0,0,0}, hn = {0,0,0,0};

    {
        const int xrow = triples[(brow + r16) * 3 + 1];
        const float* xp = map + (size_t)xrow * EE;
        #pragma unroll
        for (int kk = 0; kk < 7; kk++) {
            short8v a0, a1;
            #pragma unroll
            for (int e = 0; e < 8; e++) {
                int k = kk * 32 + kq * 8 + e;
                float v = (k < EE) ? xp[k] : 0.0f;
                unsigned short hhh = f2bf(v);
                a0[e] = (short)hhh;
                a1[e] = (short)f2bf(v - bf2f(hhh));
            }
            const size_t rowr = (size_t)(jf * 16 + r16) * KP + kk * 32 + kq * 8;
            const size_t rowz = rowr + (size_t)224 * KP;
            const size_t rown = rowr + (size_t)448 * KP;
            short8v brh = *(const short8v*)(Wihi + rowr);
            short8v brl = *(const short8v*)(Wilo + rowr);
            short8v bzh = *(const short8v*)(Wihi + rowz);
            short8v bzl = *(const short8v*)(Wilo + rowz);
            short8v bnh = *(const short8v*)(Wihi + rown);
            short8v bnl = *(const short8v*)(Wilo + rown);
            ir = __builtin_amdgcn_mfma_f32_16x16x32_bf16(a0, brl, ir, 0, 0, 0);
            iz = __builtin_amdgcn_mfma_f32_16x16x32_bf16(a0, bzl, iz, 0, 0, 0);
            in_ = __builtin_amdgcn_mfma_f32_16x16x32_bf16(a0, bnl, in_, 0, 0, 0);
            ir = __builtin_amdgcn_mfma_f32_16x16x32_bf16(a1, brh, ir, 0, 0, 0);
            iz = __builtin_amdgcn_mfma_f32_16x16x32_bf16(a1, bzh, iz, 0, 0, 0);
            in_ = __builtin_amdgcn_mfma_f32_16x16x32_bf16(a1, bnh, in_, 0, 0, 0);
            ir = __builtin_amdgcn_mfma_f32_16x16x32_bf16(a0, brh, ir, 0, 0, 0);
            iz = __builtin_amdgcn_mfma_f32_16x16x32_bf16(a0, bzh, iz, 0, 0, 0);
            in_ = __builtin_amdgcn_mfma_f32_16x16x32_bf16(a0, bnh, in_, 0, 0, 0);
        }
    }
    {
        const float* hpp = hp + (size_t)(brow + r16) * EE;
        #pragma unroll
        for (int kk = 0; kk < 7; kk++) {
            short8v a0, a1;
            #pragma unroll
            for (int e = 0; e < 8; e++) {
                int k = kk * 32 + kq * 8 + e;
                float v = (k < EE) ? hpp[k] : 0.0f;
                unsigned short hhh = f2bf(v);
                a0[e] = (short)hhh;
                a1[e] = (short)f2bf(v - bf2f(hhh));
            }
            const size_t rowr = (size_t)(jf * 16 + r16) * KP + kk * 32 + kq * 8;
            const size_t rowz = rowr + (size_t)224 * KP;
            const size_t rown = rowr + (size_t)448 * KP;
            short8v brh = *(const short8v*)(Whhi + rowr);
            short8v brl = *(const short8v*)(Whlo + rowr);
            short8v bzh = *(const short8v*)(Whhi + rowz);
            short8v bzl = *(const short8v*)(Whlo + rowz);
            short8v bnh = *(const short8v*)(Whhi + rown);
            short8v bnl = *(const short8v*)(Whlo + rown);
            hr = __builtin_amdgcn_mfma_f32_16x16x32_bf16(a0, brl, hr, 0, 0, 0);
            hz = __builtin_amdgcn_mfma_f32_16x16x32_bf16(a0, bzl, hz, 0, 0, 0);
            hn = __builtin_amdgcn_mfma_f32_16x16x32_bf16(a0, bnl, hn, 0, 0, 0);
            hr = __builtin_amdgcn_mfma_f32_16x16x32_bf16(a1, brh, hr, 0, 0, 0);
            hz = __builtin_amdgcn_mfma_f32_16x16x32_bf16(a1, bzh, hz, 0, 0, 0);
            hn = __builtin_amdgcn_mfma_f32_16x16x32_bf16(a1, bnh, hn, 0, 0, 0);
            hr = __builtin_amdgcn_mfma_f32_16x16x32_bf16(a0, brh, hr, 0, 0, 0);
            hz = __builtin_amdgcn_mfma_f32_16x16x32_bf16(a0, bzh, hz, 0, 0, 0);
            hn = __builtin_amdgcn_mfma_f32_16x16x32_bf16(a0, bnh, hn, 0, 0, 0);
        }
    }

    float psum = 0.0f;
    if (j < EE) {
        const float bir = bih_pad[j], biz = bih_pad[224 + j], bin = bih_pad[448 + j];
        const float bhr = bhh_pad[j], bhz = bhh_pad[224 + j], bhn = bhh_pad[448 + j];
        #pragma unroll
        for (int q = 0; q < 4; q++) {
            const int row = brow + kq * 4 + q;
            float r_ = sigm(ir[q] + bir + hr[q] + bhr);
            float z_ = sigm(iz[q] + biz + hz[q] + bhz);
            float n_ = tanhf(in_[q] + bin + r_ * (hn[q] + bhn));
            float hold = hp[(size_t)row * EE + j];
            ghid2[(size_t)row * EE + j] = (1.0f - z_) * n_ + z_ * hold;
            float d = hold - hfin[(size_t)row * EE + j];
            psum += d * d;
        }
    }
    red[tid] = psum;
    __syncthreads();
    for (int s = 128; s > 0; s >>= 1) {
        if (tid < s) red[tid] += red[tid + s];
        __syncthreads();
    }
    if (tid == 0) atomicAdd(accMatch, (double)red[0]);
}

// ---------------------------------------------------------------------------
// score = sigmoid(u @ pre_emb^T) with SWAPPED MFMA operands (A = pre, B = U)
// so each lane's 4 acc regs are CONSECUTIVE output columns -> float4 stores,
// and a wave fills 1600 B contiguous per output row in rapid succession.
// Grid (100 pre-chunks of 400, 16 u-groups of 64) x 256 (4 waves x 16 u-rows).
__global__ __launch_bounds__(256) void score_mfma4_kernel(
    const unsigned short* __restrict__ Ubf,   // [BB][KP] bf16 (col200 = s1h.bal)
    const float* __restrict__ pre_emb,        // [NN][EE] fp32 (L3-resident)
    const int* __restrict__ triples,
    float* __restrict__ outScore,             // [BB][NN]
    double* __restrict__ accPath)
{
    __shared__ float red[256];
    const int tid = threadIdx.x;
    const int wave = tid >> 6, lane = tid & 63;
    const int r16 = lane & 15, kq = lane >> 4;
    const int kbase = kq * 8;
    const int pc = blockIdx.x * 400;          // pre-chunk base
    const int u0 = blockIdx.y * 64 + wave * 16;

    // B = U rows u0..u0+15 -> registers
    short8v bU[7];
    {
        const unsigned short* Up = Ubf + (size_t)(u0 + r16) * KP + kbase;
        #pragma unroll
        for (int kk = 0; kk < 7; kk++) bU[kk] = *(const short8v*)(Up + kk * 32);
    }
    const int myUrow = u0 + r16;              // output row for this lane (col=lane&15)
    const int objc = triples[myUrow * 3 + 2];

    float psum = 0.0f;

    #pragma unroll
    for (int m = 0; m < 25; m++) {
        const int prow = pc + m * 16 + r16;   // A row (pre row) for this lane
        const float* Pp = pre_emb + (size_t)prow * EE;
        f32x4 acc = {0, 0, 0, 0};
        #pragma unroll
        for (int kk = 0; kk < 7; kk++) {
            short8v a;
            if (kk < 6) {
                const float* src = Pp + kk * 32 + kbase;
                float4 v0 = *(const float4*)(src);
                float4 v1 = *(const float4*)(src + 4);
                a[0] = (short)f2bf(v0.x); a[1] = (short)f2bf(v0.y);
                a[2] = (short)f2bf(v0.z); a[3] = (short)f2bf(v0.w);
                a[4] = (short)f2bf(v1.x); a[5] = (short)f2bf(v1.y);
                a[6] = (short)f2bf(v1.z); a[7] = (short)f2bf(v1.w);
            } else {
                // k = 192 + kq*8 + e : valid <200, ==200 -> 1.0 (bal fold), else 0
                #pragma unroll
                for (int e = 0; e < 8; e++) {
                    int k = 192 + kq * 8 + e;
                    float v = (k < EE) ? Pp[k] : ((k == EE) ? 1.0f : 0.0f);
                    a[e] = (short)f2bf(v);
                }
            }
            acc = __builtin_amdgcn_mfma_f32_16x16x32_bf16(a, bU[kk], acc, 0, 0, 0);
        }
        // epilogue: 4 consecutive output cols in row myUrow
        const int cbase = pc + m * 16 + kq * 4;
        float4 ov;
        float* op = (float*)&ov;
        #pragma unroll
        for (int r = 0; r < 4; r++) {
            const int col = cbase + r;
            float x  = acc[r];
            float e  = __expf(-fabsf(x));
            float t1 = 1.0f + e;
            float rc = __builtin_amdgcn_rcpf(t1);
            float sig = (x >= 0.0f) ? rc : e * rc;
            float sp = __logf(t1);
            float s  = (col == objc) ? x : -x;
            psum += fminf(s, 0.0f) - sp;
            op[r] = sig;
        }
        *(float4*)&outScore[(size_t)myUrow * NN + cbase] = ov;
    }

    red[tid] = psum;
    __syncthreads();
    for (int s = 128; s > 0; s >>= 1) {
        if (tid < s) red[tid] += red[tid + s];
        __syncthreads();
    }
    if (tid == 0) atomicAdd(accPath, (double)red[0]);
}

// ---------------------------------------------------------------------------
__global__ __launch_bounds__(256) void masked_softmax_all_kernel(
    const float* __restrict__ base, const float* __restrict__ part,
    unsigned short* __restrict__ aout_hi)
{
    __shared__ float sv[RR];
    __shared__ float red[256];
    const int blk = blockIdx.x;
    const int b = blk & (BB - 1);
    const int t = blk >> 10;
    const int tid = threadIdx.x;
    const float* brow = base + (size_t)b * RR;
    const float* prow = part + (size_t)b * (TT * RR) + t * RR;

    float lmax = -3.0e38f;
    for (int r = tid; r < RR; r += 256) {
        float v = prow[r] * brow[r];
        if (v == 0.0f) v = -1000000000.0f;
        sv[r] = v;
        lmax = fmaxf(lmax, v);
    }
    red[tid] = lmax;
    __syncthreads();
    for (int s = 128; s > 0; s >>= 1) {
        if (tid < s) red[tid] = fmaxf(red[tid], red[tid + s]);
        __syncthreads();
    }
    float gmax = red[0];
    __syncthreads();

    float lsum = 0.0f;
    for (int r = tid; r < RR; r += 256) {
        float e = __expf(sv[r] - gmax);
        sv[r] = e;
        lsum += e;
    }
    red[tid] = lsum;
    __syncthreads();
    for (int s = 128; s > 0; s >>= 1) {
        if (tid < s) red[tid] += red[tid + s];
        __syncthreads();
    }
    float inv = 1.0f / red[0];
    for (int r = tid; r < RR; r += 256)
        aout_hi[(size_t)blk * RR + r] = f2bf(sv[r] * inv);
}

__global__ void final_kernel(const double* __restrict__ acc, float* __restrict__ out)
{
    if (threadIdx.x == 0) {
        out[0] = (float)(acc[0] / ((double)BB * EE));
        out[1] = (float)(-acc[1] / ((double)BB * NN));
    }
}

// ---------------------------------------------------------------------------
extern "C" void kernel_launch(void* const* d_in, const int* in_sizes, int n_in,
                              void* d_out, int out_size, void* d_ws, size_t ws_size,
                              hipStream_t stream) {
    const float* pre_emb = (const float*)d_in[0];
    const float* r_emb   = (const float*)d_in[1];
    const float* part    = (const float*)d_in[2];
    const int*   triples = (const int*)d_in[3];
    const float* W1  = (const float*)d_in[6];
    const float* b1  = (const float*)d_in[7];
    const float* W2  = (const float*)d_in[8];
    const float* b2  = (const float*)d_in[9];
    const float* Wa  = (const float*)d_in[10];
    const float* ba  = (const float*)d_in[11];
    const float* Wh1 = (const float*)d_in[12];
    const float* bh1 = (const float*)d_in[13];
    const float* Wh2 = (const float*)d_in[14];
    const float* bh2 = (const float*)d_in[15];
    const float* Wal = (const float*)d_in[16];
    const float* bal = (const float*)d_in[17];
    const float* wih = (const float*)d_in[18];
    const float* whh = (const float*)d_in[19];
    const float* bih = (const float*)d_in[20];
    const float* bhh = (const float*)d_in[21];

    float* out = (float*)d_out;
    double* acc = (double*)d_ws;
    float* wsf = (float*)d_ws;
    size_t off = 4;
    auto alloc = [&](size_t n) { float* p = wsf + off; off += (n + 3) & ~(size_t)3; return p; };
    auto allocS = [&](size_t n) { return (unsigned short*)alloc((n + 1) / 2); };

    PrepPtrs p;
    p.W1h  = allocS((size_t)448 * 224);
    p.W1l  = allocS((size_t)448 * 224);
    p.W2h  = allocS((size_t)256 * 416);
    p.W2l  = allocS((size_t)256 * 416);
    p.Wabh = allocS((size_t)448 * 224);
    p.Wabl = allocS((size_t)448 * 224);
    p.Wh2h = allocS((size_t)256 * 224);
    p.Wh2l = allocS((size_t)256 * 224);
    p.Walh = allocS((size_t)256 * 224);
    p.Wall = allocS((size_t)256 * 224);
    p.WTh  = allocS((size_t)256 * 224);
    p.WTl  = allocS((size_t)256 * 224);
    p.wgh  = allocS((size_t)GP * KP);
    p.wgl  = allocS((size_t)GP * KP);
    p.whg  = allocS((size_t)GP * KP);
    p.whl  = allocS((size_t)GP * KP);
    p.bab  = alloc(448);
    p.bihp = alloc(GPR);
    p.bhhp = alloc(GP);
    p.mapSh = allocS((size_t)512 * 224);
    p.mapSl = allocS((size_t)512 * 224);
    p.wgiSh = allocS((size_t)GPR * RR);
    p.wgiSl = allocS((size_t)GPR * RR);
    p.hbufs = allocS((size_t)4 * BB * KP);
    p.acc = acc;

    unsigned short* ha_hi = p.hbufs;
    unsigned short* ha_lo = p.hbufs + (size_t)BB * KP;
    unsigned short* hb_hi = p.hbufs + (size_t)2 * BB * KP;
    unsigned short* hb_lo = p.hbufs + (size_t)3 * BB * KP;

    float* h1     = alloc((size_t)RR * 400);
    float* map    = alloc((size_t)RR * EE);
    float* qa_ph1 = alloc((size_t)BB * 448);
    float* basep  = alloc((size_t)BB * RR);
    unsigned short* aw_hi = allocS((size_t)TT * BB * RR);
    float* gi_all = alloc((size_t)TT * BB * GP);
    float* hfin   = alloc((size_t)BB * EE);
    float* pred   = alloc((size_t)BB * EE);
    float* ghid2  = alloc((size_t)BB * EE);
    float* s1h    = alloc((size_t)BB * EE);
    unsigned short* u_bf = allocS((size_t)BB * KP);

    dim3 blk(256);

    // 1. all prep in one launch
    prep_kernel<<<1024, blk, 0, stream>>>(
        W1, W2, Wa, Wh1, Wh2, Wal, bal, wih, whh, ba, bh1, bih, bhh, p);

    // 2. h1 = r_emb @ W1^T + b1   (480 x 400, K=200)
    mfma_flyA<0,0,0,0,0><<<dim3(7, 8), blk, 0, stream>>>(
        r_emb, 200, nullptr, 0, p.W1h, p.W1l, b1, h1, nullptr, nullptr,
        RR, 400, 200, 224, nullptr, 0, 0.f, 0);
    // 3. map = h1 @ W2^T + b2     (480 x 200, K=400) + hi/lo split
    mfma_flyA<0,3,0,0,0><<<dim3(4, 8), blk, 0, stream>>>(
        h1, 400, nullptr, 0, p.W2h, p.W2l, b2, map, p.mapSh, p.mapSl,
        RR, EE, 400, 416, nullptr, 0, 0.f, 224);
    // 4. qa_ph1 = map[rel] @ [Wa ; Wh1]^T + [ba ; bh1]  (1024 x 448)
    mfma_flyA<0,0,1,0,0><<<dim3(7, 16), blk, 0, stream>>>(
        map, 200, triples, 1, p.Wabh, p.Wabl, p.bab, qa_ph1, nullptr, nullptr,
        BB, 448, 200, 224, nullptr, 0, 0.f, 0);
    // 5. basep = qa @ map^T       (1024 x 480)
    mfma_flyA<0,0,0,0,0><<<dim3(8, 16), blk, 0, stream>>>(
        qa_ph1, 448, nullptr, 0, p.mapSh, p.mapSl, nullptr, basep, nullptr, nullptr,
        BB, RR, 200, 224, nullptr, 0, 0.f, 0);
    // 6. all-t masked softmax -> bf16 (hi only)
    masked_softmax_all_kernel<<<TT * BB, blk, 0, stream>>>(basep, part, aw_hi);
    // 7. Wgi = wih @ map^T  (600 x 480) -> gate-padded hi/lo
    mfma_flyA<0,2,0,1,0><<<dim3(8, 10), blk, 0, stream>>>(
        wih, 200, nullptr, 0, p.mapSh, p.mapSl, nullptr, nullptr, p.wgiSh, p.wgiSl,
        600, RR, 200, 224, nullptr, 0, 0.f, RR);
    // 8. gi_all = aw_all @ Wgi^T + bih  (8192 x 672, Ks=480) bf16x1
    mfma_linear1_kernel<<<dim3(11, TT * BB / 64), blk, 0, stream>>>(
        aw_hi, p.wgiSh, p.bihp, gi_all, TT * BB, GP, RR);

    // 9-16. GRU scan: 8 wide fused launches, t=0 skips the h-GEMM (h0 = 0).
    for (int t = 0; t < TT; t++) {
        const float* gi_t = gi_all + (size_t)t * BB * GP;
        const unsigned short* ih = (t & 1) ? hb_hi : ha_hi;
        const unsigned short* il = (t & 1) ? hb_lo : ha_lo;
        unsigned short* oh = (t & 1) ? ha_hi : hb_hi;
        unsigned short* ol = (t & 1) ? ha_lo : hb_lo;
        if (t == 0)
            gru_step_kernel<1,0><<<dim3(13, BB / 64), blk, 0, stream>>>(
                p.whg, p.whl, p.bhhp, gi_t, ih, il, oh, ol, nullptr);
        else if (t == TT - 1)
            gru_step_kernel<0,1><<<dim3(13, BB / 64), blk, 0, stream>>>(
                p.whg, p.whl, p.bhhp, gi_t, ih, il, oh, ol, hfin);
        else
            gru_step_kernel<0,0><<<dim3(13, BB / 64), blk, 0, stream>>>(
                p.whg, p.whl, p.bhhp, gi_t, ih, il, oh, ol, nullptr);
    }

    // 17. pred = 0.1*(ph1 @ Wh2^T + bh2) + map[rel]
    mfma_flyA<1,0,0,0,1><<<dim3(4, 16), blk, 0, stream>>>(
        qa_ph1 + 224, 448, triples, 1, p.Wh2h, p.Wh2l, bh2, pred, nullptr, nullptr,
        BB, EE, 200, 224, map, 200, 0.1f, 0);
    // 18. gru_hidden2 fused + match-loss partial
    gru2_fused_kernel<<<dim3(13, BB / 64), blk, 0, stream>>>(
        p.wgh, p.wgl, p.whg, p.whl, p.bihp, p.bhhp,
        triples, map, pred, hfin, ghid2, acc + 0);
    // 19. s1h = (pre_emb[sub] @ Wal^T + bal) * ghid2
    mfma_flyA<2,0,1,0,0><<<dim3(4, 16), blk, 0, stream>>>(
        pre_emb, 200, triples, 0, p.Walh, p.Wall, bal, s1h, nullptr, nullptr,
        BB, EE, 200, 224, ghid2, 200, 0.f, 0);
    // 20. u = s1h @ [Wal^T ; bal] -> bf16 [1024][224]
    mfma_flyA<0,1,0,0,0><<<dim3(4, 16), blk, 0, stream>>>(
        s1h, 200, nullptr, 0, p.WTh, p.WTl, nullptr, nullptr, u_bf, nullptr,
        BB, KP, 200, 224, nullptr, 0, 0.f, KP);
    // 21. score + path loss: swapped-operand, float4 row-contiguous stores
    score_mfma4_kernel<<<dim3(100, 16), blk, 0, stream>>>(u_bf, pre_emb, triples, out + 2, acc + 1);
    // 22. finalize
    final_kernel<<<1, 64, 0, stream>>>(acc, out);
}

// Round 15
// 395.955 us; speedup vs baseline: 1.4683x; 1.4683x over previous
//
#include <hip/hip_runtime.h>
#include <hip/hip_bf16.h>
#include <math.h>

// Problem constants
#define EE 200
#define RR 480
#define TT 8
#define NN 40000
#define BB 1024
#define KP 224          // K=200 padded to 32-multiple
#define GP 672          // gate-padded width: 3 x 224
#define GPR 704         // 11*64 row padding for 672-col MFMA tiles
#define LDS_STRIDE 232  // shorts per LDS row in score kernel

typedef __attribute__((ext_vector_type(8))) short short8v;   // 8 bf16
typedef __attribute__((ext_vector_type(4))) float f32x4;

__device__ inline unsigned short f2bf(float x) {  // RNE fp32->bf16
    unsigned int u = __float_as_uint(x);
    unsigned int r = ((u >> 16) & 1u) + 0x7fffu;
    return (unsigned short)((u + r) >> 16);
}
__device__ inline float bf2f(unsigned short h) {
    return __uint_as_float(((unsigned int)h) << 16);
}
__device__ inline float sigm(float x) { return 1.0f / (1.0f + __expf(-x)); }
__device__ inline void split_store(unsigned short* hi, unsigned short* lo, size_t i, float v) {
    unsigned short h = f2bf(v);
    hi[i] = h;
    lo[i] = f2bf(v - bf2f(h));
}

// ---------------------------------------------------------------------------
struct PrepPtrs {
    unsigned short *W1h, *W1l, *W2h, *W2l, *Wabh, *Wabl, *Wh2h, *Wh2l;
    unsigned short *Walh, *Wall, *WTh, *WTl, *wgh, *wgl, *whg, *whl;
    float *bab, *bihp, *bhhp;
    unsigned short *mapSh, *mapSl, *wgiSh, *wgiSl, *hbufs;
    double* acc;
};

// One-shot prep: all weight hi/lo splits (padded), bias pads, arena zeroing.
__global__ __launch_bounds__(256) void prep_kernel(
    const float* __restrict__ W1, const float* __restrict__ W2,
    const float* __restrict__ Wa, const float* __restrict__ Wh1,
    const float* __restrict__ Wh2, const float* __restrict__ Wal,
    const float* __restrict__ bal, const float* __restrict__ wih,
    const float* __restrict__ whh, const float* __restrict__ ba,
    const float* __restrict__ bh1, const float* __restrict__ bih,
    const float* __restrict__ bhh, PrepPtrs p)
{
    const int gt = blockIdx.x * 256 + threadIdx.x;
    const int gs = gridDim.x * 256;

    for (int i = gt; i < 448 * 224; i += gs) {
        int r = i / 224, c = i - r * 224;
        split_store(p.W1h, p.W1l, i, (r < 400 && c < 200) ? W1[r * 200 + c] : 0.f);
        // Wab: rows 0..199 = Wa, rows 224..423 = Wh1
        float vab = 0.f;
        if (c < 200) {
            if (r < 200) vab = Wa[r * 200 + c];
            else if (r >= 224 && r < 424) vab = Wh1[(r - 224) * 200 + c];
        }
        split_store(p.Wabh, p.Wabl, i, vab);
    }
    for (int i = gt; i < 256 * 416; i += gs) {
        int r = i / 416, c = i - r * 416;
        split_store(p.W2h, p.W2l, i, (r < 200 && c < 400) ? W2[r * 400 + c] : 0.f);
    }
    for (int i = gt; i < 256 * 224; i += gs) {
        int r = i / 224, c = i - r * 224;
        bool in = (r < 200 && c < 200);
        split_store(p.Wh2h, p.Wh2l, i, in ? Wh2[r * 200 + c] : 0.f);
        split_store(p.Walh, p.Wall, i, in ? Wal[r * 200 + c] : 0.f);
        float vt = in ? Wal[c * 200 + r] : ((r == 200 && c < 200) ? bal[c] : 0.f);
        split_store(p.WTh, p.WTl, i, vt);
    }
    for (int i = gt; i < 672 * 224; i += gs) {
        int rr = i / 224, c = i - rr * 224;
        int g = rr / 224, j = rr - g * 224;
        bool in = (j < 200 && c < 200);
        split_store(p.wgh, p.wgl, i, in ? wih[(size_t)(g * 200 + j) * 200 + c] : 0.f);
        split_store(p.whg, p.whl, i, in ? whh[(size_t)(g * 200 + j) * 200 + c] : 0.f);
    }
    for (int i = gt; i < 448; i += gs) {
        float v = 0.f;
        if (i < 200) v = ba[i];
        else if (i >= 224 && i < 424) v = bh1[i - 224];
        p.bab[i] = v;
    }
    for (int i = gt; i < GPR; i += gs) {
        int g = i / 224, j = i - g * 224;
        p.bihp[i] = (g < 3 && j < 200) ? bih[g * 200 + j] : 0.f;
    }
    for (int i = gt; i < GP; i += gs) {
        int g = i / 224, j = i - g * 224;
        p.bhhp[i] = (j < 200) ? bhh[g * 200 + j] : 0.f;
    }
    for (int i = gt; i < 512 * 224; i += gs) { p.mapSh[i] = 0; p.mapSl[i] = 0; }
    for (int i = gt; i < 704 * 480; i += gs) { p.wgiSh[i] = 0; p.wgiSl[i] = 0; }
    for (int i = gt; i < 4 * BB * KP; i += gs) p.hbufs[i] = 0;
    if (gt == 0) { p.acc[0] = 0.0; p.acc[1] = 0.0; }
}

// ---------------------------------------------------------------------------
// bf16x3 MFMA linear with on-the-fly A conversion (fp32 A, pre-split B).
// C = A @ (Bhi+Blo)^T (+bias). Grid (ceil(N/64), ceil(M/64)) x 256.
// MODE 0: +bias ; 1: alpha*(acc+bias)+extra ; 2: (acc+bias)*extra
// OUT 0: fp32 (stride N). 1: bf16 [obf stride]. 2: hi/lo split (+GATEPAD).
//     3: fp32 (stride N) + hi/lo split [obf].
// GATHER: A row = gidx[row*3+gsel]. EGATHER: extra row = gidx[orow*3+gsel].
template <int MODE, int OUT, int GATHER, int GATEPAD, int EGATHER>
__global__ __launch_bounds__(256) void mfma_flyA(
    const float* __restrict__ A, int lda, const int* __restrict__ gidx, int gsel,
    const unsigned short* __restrict__ Bhi, const unsigned short* __restrict__ Blo,
    const float* __restrict__ bias,
    float* __restrict__ Cf, unsigned short* __restrict__ Chi, unsigned short* __restrict__ Clo,
    int M, int N, int Ka, int Ks,
    const float* __restrict__ extra, int eld, float alpha, int obf)
{
    const int tid = threadIdx.x;
    const int wave = tid >> 6, lane = tid & 63;
    const int r16 = lane & 15, kq = lane >> 4;
    const int kbase = kq * 8;
    const int bm = blockIdx.y * 64 + wave * 16;
    const int bn = blockIdx.x * 64;

    int arow = bm + r16;
    const bool avalid = arow < M;
    if (GATHER) { if (avalid) arow = gidx[arow * 3 + gsel]; }
    const float* Ap = A + (size_t)arow * lda;

    f32x4 acc[4] = {{0,0,0,0},{0,0,0,0},{0,0,0,0},{0,0,0,0}};
    const int nk = Ks >> 5;

    for (int kk = 0; kk < nk; kk++) {
        const int k0 = kk * 32 + kbase;
        short8v a0, a1;
        #pragma unroll
        for (int e = 0; e < 8; e++) {
            float v = (avalid && (k0 + e) < Ka) ? Ap[k0 + e] : 0.f;
            unsigned short h = f2bf(v);
            a0[e] = (short)h;
            a1[e] = (short)f2bf(v - bf2f(h));
        }
        #pragma unroll
        for (int nf = 0; nf < 4; nf++) {
            const size_t boff = (size_t)(bn + nf * 16 + r16) * Ks + k0;
            short8v b0 = *(const short8v*)(Bhi + boff);
            short8v b1 = *(const short8v*)(Blo + boff);
            acc[nf] = __builtin_amdgcn_mfma_f32_16x16x32_bf16(a0, b1, acc[nf], 0, 0, 0);
            acc[nf] = __builtin_amdgcn_mfma_f32_16x16x32_bf16(a1, b0, acc[nf], 0, 0, 0);
            acc[nf] = __builtin_amdgcn_mfma_f32_16x16x32_bf16(a0, b0, acc[nf], 0, 0, 0);
        }
    }

    #pragma unroll
    for (int r = 0; r < 4; r++) {
        const int orow = bm + kq * 4 + r;
        if (orow >= M) continue;
        #pragma unroll
        for (int nf = 0; nf < 4; nf++) {
            const int col = bn + nf * 16 + r16;
            float v = acc[nf][r];
            if (OUT == 0) {
                if (col < N) {
                    if (bias) v += bias[col];
                    if (MODE == 1) {
                        float ex = EGATHER ? extra[(size_t)gidx[orow * 3 + gsel] * eld + col]
                                           : extra[(size_t)orow * eld + col];
                        v = alpha * v + ex;
                    } else if (MODE == 2) {
                        v = v * extra[(size_t)orow * eld + col];
                    }
                    Cf[(size_t)orow * N + col] = v;
                }
            } else if (OUT == 1) {
                if (col < obf) {
                    float w = 0.f;
                    if (col < N) { w = v; if (bias) w += bias[col]; }
                    Chi[(size_t)orow * obf + col] = f2bf(w);
                }
            } else if (OUT == 2) {
                if (col < N) {
                    int wr = GATEPAD ? (orow / 200) * 224 + orow % 200 : orow;
                    if (bias) v += bias[col];
                    split_store(Chi, Clo, (size_t)wr * obf + col, v);
                }
            } else if (OUT == 3) {
                if (col < N) {
                    if (bias) v += bias[col];
                    Cf[(size_t)orow * N + col] = v;
                    split_store(Chi, Clo, (size_t)orow * obf + col, v);
                }
            }
        }
    }
}

// ---------------------------------------------------------------------------
// bf16x1 MFMA linear: C = A_hi @ B_hi^T + bias (both already bf16).
__global__ __launch_bounds__(256) void mfma_linear1_kernel(
    const unsigned short* __restrict__ Ahi,
    const unsigned short* __restrict__ Bhi,
    const float* __restrict__ bias, float* __restrict__ C,
    int M, int N, int Ks)
{
    const int tid  = threadIdx.x;
    const int wave = tid >> 6;
    const int lane = tid & 63;
    const int r16   = lane & 15;
    const int khalf = lane >> 4;
    const int kbase = khalf * 8;
    const int bm = blockIdx.y * 64 + wave * 16;
    const int bn = blockIdx.x * 64;

    const unsigned short* ah = Ahi + (size_t)(bm + r16) * Ks + kbase;
    const unsigned short* bh = Bhi + (size_t)(bn + r16) * Ks + kbase;

    f32x4 acc[4] = {{0,0,0,0},{0,0,0,0},{0,0,0,0},{0,0,0,0}};

    for (int k0 = 0; k0 < Ks; k0 += 32) {
        short8v a0 = *(const short8v*)(ah + k0);
        #pragma unroll
        for (int nf = 0; nf < 4; nf++) {
            short8v b0 = *(const short8v*)(bh + (size_t)nf * 16 * Ks + k0);
            acc[nf] = __builtin_amdgcn_mfma_f32_16x16x32_bf16(a0, b0, acc[nf], 0, 0, 0);
        }
    }
    #pragma unroll
    for (int r = 0; r < 4; r++) {
        const int row = bm + khalf * 4 + r;
        #pragma unroll
        for (int nf = 0; nf < 4; nf++) {
            const int col = bn + nf * 16 + r16;
            if (col < N)
                C[(size_t)row * N + col] = acc[nf][r] + (bias ? bias[col] : 0.0f);
        }
    }
}

// ---------------------------------------------------------------------------
// One GRU step (fused gh-GEMM + combine), grid (13, 16) x 256.
// FIRST=1: h_in == 0, skip the h-GEMM entirely. LAST=1: also write fp32 h.
template <int FIRST, int LAST>
__global__ __launch_bounds__(256) void gru_step_kernel(
    const unsigned short* __restrict__ Whi, const unsigned short* __restrict__ Wlo,
    const float* __restrict__ bhh_pad,
    const float* __restrict__ gi_t,
    const unsigned short* __restrict__ hin_hi, const unsigned short* __restrict__ hin_lo,
    unsigned short* __restrict__ hout_hi, unsigned short* __restrict__ hout_lo,
    float* __restrict__ h_fin)
{
    const int tid = threadIdx.x;
    const int wave = tid >> 6, lane = tid & 63;
    const int r16 = lane & 15, kq = lane >> 4;
    const int jf = blockIdx.x;
    const int brow = (blockIdx.y * 4 + wave) * 16;
    const int j = jf * 16 + r16;

    f32x4 ar = {0,0,0,0}, az = {0,0,0,0}, an = {0,0,0,0};
    if (!FIRST) {
        short8v ahi[7], alo[7];
        const unsigned short* hh = hin_hi + (size_t)(brow + r16) * KP + kq * 8;
        const unsigned short* hl = hin_lo + (size_t)(brow + r16) * KP + kq * 8;
        #pragma unroll
        for (int kk = 0; kk < 7; kk++) {
            ahi[kk] = *(const short8v*)(hh + kk * 32);
            alo[kk] = *(const short8v*)(hl + kk * 32);
        }
        #pragma unroll
        for (int kk = 0; kk < 7; kk++) {
            const size_t rowr = (size_t)(jf * 16 + r16) * KP + kk * 32 + kq * 8;
            const size_t rowz = rowr + (size_t)224 * KP;
            const size_t rown = rowr + (size_t)448 * KP;
            short8v brh = *(const short8v*)(Whi + rowr);
            short8v brl = *(const short8v*)(Wlo + rowr);
            short8v bzh = *(const short8v*)(Whi + rowz);
            short8v bzl = *(const short8v*)(Wlo + rowz);
            short8v bnh = *(const short8v*)(Whi + rown);
            short8v bnl = *(const short8v*)(Wlo + rown);
            ar = __builtin_amdgcn_mfma_f32_16x16x32_bf16(ahi[kk], brl, ar, 0, 0, 0);
            az = __builtin_amdgcn_mfma_f32_16x16x32_bf16(ahi[kk], bzl, az, 0, 0, 0);
            an = __builtin_amdgcn_mfma_f32_16x16x32_bf16(ahi[kk], bnl, an, 0, 0, 0);
            ar = __builtin_amdgcn_mfma_f32_16x16x32_bf16(alo[kk], brh, ar, 0, 0, 0);
            az = __builtin_amdgcn_mfma_f32_16x16x32_bf16(alo[kk], bzh, az, 0, 0, 0);
            an = __builtin_amdgcn_mfma_f32_16x16x32_bf16(alo[kk], bnh, an, 0, 0, 0);
            ar = __builtin_amdgcn_mfma_f32_16x16x32_bf16(ahi[kk], brh, ar, 0, 0, 0);
            az = __builtin_amdgcn_mfma_f32_16x16x32_bf16(ahi[kk], bzh, az, 0, 0, 0);
            an = __builtin_amdgcn_mfma_f32_16x16x32_bf16(ahi[kk], bnh, an, 0, 0, 0);
        }
    }

    const float br = bhh_pad[j], bz = bhh_pad[224 + j], bn_ = bhh_pad[448 + j];
    #pragma unroll
    for (int q = 0; q < 4; q++) {
        const int row = brow + kq * 4 + q;
        float gir = gi_t[(size_t)row * GP + j];
        float giz = gi_t[(size_t)row * GP + 224 + j];
        float gin = gi_t[(size_t)row * GP + 448 + j];
        float r_ = sigm(gir + ar[q] + br);
        float z_ = sigm(giz + az[q] + bz);
        float n_ = tanhf(gin + r_ * (an[q] + bn_));
        float hold = 0.0f;
        if (!FIRST)
            hold = bf2f(hin_hi[(size_t)row * KP + j]) + bf2f(hin_lo[(size_t)row * KP + j]);
        float hnew = (1.0f - z_) * n_ + z_ * hold;
        if (j < EE) {
            unsigned short nh = f2bf(hnew);
            hout_hi[(size_t)row * KP + j] = nh;
            hout_lo[(size_t)row * KP + j] = f2bf(hnew - bf2f(nh));
            if (LAST) h_fin[(size_t)row * EE + j] = hnew;
        }
    }
}

// ---------------------------------------------------------------------------
// gru_hidden2 = gru_cell(x = map[rel], h = pred), fused; also accumulates
// match-loss partial sum sum((pred - hfin)^2).
__global__ __launch_bounds__(256) void gru2_fused_kernel(
    const unsigned short* __restrict__ Wihi, const unsigned short* __restrict__ Wilo,
    const unsigned short* __restrict__ Whhi, const unsigned short* __restrict__ Whlo,
    const float* __restrict__ bih_pad, const float* __restrict__ bhh_pad,
    const int* __restrict__ triples, const float* __restrict__ map,
    const float* __restrict__ hp, const float* __restrict__ hfin,
    float* __restrict__ ghid2, double* __restrict__ accMatch)
{
    __shared__ float red[256];
    const int tid = threadIdx.x;
    const int wave = tid >> 6, lane = tid & 63;
    const int r16 = lane & 15, kq = lane >> 4;
    const int jf = blockIdx.x;
    const int brow = (blockIdx.y * 4 + wave) * 16;
    const int j = jf * 16 + r16;

    f32x4 ir = {0,0,0,0}, iz = {0,0,0,0}, in_ = {0,0,0,0};
    f32x4 hr = {0,0,0,0}, hz = {0,0,0,0}, hn = {0,0,0,0};

    {
        const int xrow = triples[(brow + r16) * 3 + 1];
        const float* xp = map + (size_t)xrow * EE;
        #pragma unroll
        for (int kk = 0; kk < 7; kk++) {
            short8v a0, a1;
            #pragma unroll
            for (int e = 0; e < 8; e++) {
                int k = kk * 32 + kq * 8 + e;
                float v = (k < EE) ? xp[k] : 0.0f;
                unsigned short hhh = f2bf(v);
                a0[e] = (short)hhh;
                a1[e] = (short)f2bf(v - bf2f(hhh));
            }
            const size_t rowr = (size_t)(jf * 16 + r16) * KP + kk * 32 + kq * 8;
            const size_t rowz = rowr + (size_t)224 * KP;
            const size_t rown = rowr + (size_t)448 * KP;
            short8v brh = *(const short8v*)(Wihi + rowr);
            short8v brl = *(const short8v*)(Wilo + rowr);
            short8v bzh = *(const short8v*)(Wihi + rowz);
            short8v bzl = *(const short8v*)(Wilo + rowz);
            short8v bnh = *(const short8v*)(Wihi + rown);
            short8v bnl = *(const short8v*)(Wilo + rown);
            ir = __builtin_amdgcn_mfma_f32_16x16x32_bf16(a0, brl, ir, 0, 0, 0);
            iz = __builtin_amdgcn_mfma_f32_16x16x32_bf16(a0, bzl, iz, 0, 0, 0);
            in_ = __builtin_amdgcn_mfma_f32_16x16x32_bf16(a0, bnl, in_, 0, 0, 0);
            ir = __builtin_amdgcn_mfma_f32_16x16x32_bf16(a1, brh, ir, 0, 0, 0);
            iz = __builtin_amdgcn_mfma_f32_16x16x32_bf16(a1, bzh, iz, 0, 0, 0);
            in_ = __builtin_amdgcn_mfma_f32_16x16x32_bf16(a1, bnh, in_, 0, 0, 0);
            ir = __builtin_amdgcn_mfma_f32_16x16x32_bf16(a0, brh, ir, 0, 0, 0);
            iz = __builtin_amdgcn_mfma_f32_16x16x32_bf16(a0, bzh, iz, 0, 0, 0);
            in_ = __builtin_amdgcn_mfma_f32_16x16x32_bf16(a0, bnh, in_, 0, 0, 0);
        }
    }
    {
        const float* hpp = hp + (size_t)(brow + r16) * EE;
        #pragma unroll
        for (int kk = 0; kk < 7; kk++) {
            short8v a0, a1;
            #pragma unroll
            for (int e = 0; e < 8; e++) {
                int k = kk * 32 + kq * 8 + e;
                float v = (k < EE) ? hpp[k] : 0.0f;
                unsigned short hhh = f2bf(v);
                a0[e] = (short)hhh;
                a1[e] = (short)f2bf(v - bf2f(hhh));
            }
            const size_t rowr = (size_t)(jf * 16 + r16) * KP + kk * 32 + kq * 8;
            const size_t rowz = rowr + (size_t)224 * KP;
            const size_t rown = rowr + (size_t)448 * KP;
            short8v brh = *(const short8v*)(Whhi + rowr);
            short8v brl = *(const short8v*)(Whlo + rowr);
            short8v bzh = *(const short8v*)(Whhi + rowz);
            short8v bzl = *(const short8v*)(Whlo + rowz);
            short8v bnh = *(const short8v*)(Whhi + rown);
            short8v bnl = *(const short8v*)(Whlo + rown);
            hr = __builtin_amdgcn_mfma_f32_16x16x32_bf16(a0, brl, hr, 0, 0, 0);
            hz = __builtin_amdgcn_mfma_f32_16x16x32_bf16(a0, bzl, hz, 0, 0, 0);
            hn = __builtin_amdgcn_mfma_f32_16x16x32_bf16(a0, bnl, hn, 0, 0, 0);
            hr = __builtin_amdgcn_mfma_f32_16x16x32_bf16(a1, brh, hr, 0, 0, 0);
            hz = __builtin_amdgcn_mfma_f32_16x16x32_bf16(a1, bzh, hz, 0, 0, 0);
            hn = __builtin_amdgcn_mfma_f32_16x16x32_bf16(a1, bnh, hn, 0, 0, 0);
            hr = __builtin_amdgcn_mfma_f32_16x16x32_bf16(a0, brh, hr, 0, 0, 0);
            hz = __builtin_amdgcn_mfma_f32_16x16x32_bf16(a0, bzh, hz, 0, 0, 0);
            hn = __builtin_amdgcn_mfma_f32_16x16x32_bf16(a0, bnh, hn, 0, 0, 0);
        }
    }

    float psum = 0.0f;
    if (j < EE) {
        const float bir = bih_pad[j], biz = bih_pad[224 + j], bin = bih_pad[448 + j];
        const float bhr = bhh_pad[j], bhz = bhh_pad[224 + j], bhn = bhh_pad[448 + j];
        #pragma unroll
        for (int q = 0; q < 4; q++) {
            const int row = brow + kq * 4 + q;
            float r_ = sigm(ir[q] + bir + hr[q] + bhr);
            float z_ = sigm(iz[q] + biz + hz[q] + bhz);
            float n_ = tanhf(in_[q] + bin + r_ * (hn[q] + bhn));
            float hold = hp[(size_t)row * EE + j];
            ghid2[(size_t)row * EE + j] = (1.0f - z_) * n_ + z_ * hold;
            float d = hold - hfin[(size_t)row * EE + j];
            psum += d * d;
        }
    }
    red[tid] = psum;
    __syncthreads();
    for (int s = 128; s > 0; s >>= 1) {
        if (tid < s) red[tid] += red[tid + s];
        __syncthreads();
    }
    if (tid == 0) atomicAdd(accMatch, (double)red[0]);
}

// ---------------------------------------------------------------------------
// score = sigmoid(u @ pre_emb^T), bal folded into padding col 200.
// Grid 1250 blocks x 256 threads: 32-col stripe per block (pre staged once
// chip-wide), 16 m-iterations of 64 rows (wave-split). Best measured form.
__global__ __launch_bounds__(256) void score_mfma2_kernel(
    const unsigned short* __restrict__ Ubf,
    const float* __restrict__ pre_emb,
    const int* __restrict__ triples,
    float* __restrict__ outScore,
    double* __restrict__ accPath)
{
    __shared__ unsigned short Bs[32 * LDS_STRIDE];
    __shared__ int objs[BB];
    __shared__ float red[256];

    const int tid = threadIdx.x;
    const int bn = blockIdx.x * 32;

    for (int i = tid; i < BB; i += 256) objs[i] = triples[i * 3 + 2];

    for (int idx = tid; idx < 32 * 50; idx += 256) {
        int row = idx / 50;
        int c4 = (idx - row * 50) * 4;
        float4 v = *(const float4*)(pre_emb + (size_t)(bn + row) * EE + c4);
        unsigned short* d = &Bs[row * LDS_STRIDE + c4];
        d[0] = f2bf(v.x); d[1] = f2bf(v.y); d[2] = f2bf(v.z); d[3] = f2bf(v.w);
    }
    for (int idx = tid; idx < 32 * 24; idx += 256) {
        int row = idx / 24;
        int cc = idx - row * 24;
        Bs[row * LDS_STRIDE + 200 + cc] = (cc == 0) ? (unsigned short)0x3F80 : (unsigned short)0;
    }
    __syncthreads();

    const int wave  = tid >> 6;
    const int lane  = tid & 63;
    const int r16   = lane & 15;
    const int khalf = lane >> 4;
    const int kbase = khalf * 8;

    const unsigned short* bs0 = &Bs[( 0 + r16) * LDS_STRIDE + kbase];
    const unsigned short* bs1 = &Bs[(16 + r16) * LDS_STRIDE + kbase];

    float psum = 0.0f;

    for (int mi = 0; mi < 16; mi++) {
        const int m0 = mi * 64 + wave * 16;
        const unsigned short* Ap = Ubf + (size_t)(m0 + r16) * KP + kbase;
        f32x4 acc0 = {0,0,0,0}, acc1 = {0,0,0,0};
        #pragma unroll
        for (int k0 = 0; k0 < KP; k0 += 32) {
            short8v a  = *(const short8v*)(Ap + k0);
            short8v b0 = *(const short8v*)(bs0 + k0);
            short8v b1 = *(const short8v*)(bs1 + k0);
            acc0 = __builtin_amdgcn_mfma_f32_16x16x32_bf16(a, b0, acc0, 0, 0, 0);
            acc1 = __builtin_amdgcn_mfma_f32_16x16x32_bf16(a, b1, acc1, 0, 0, 0);
        }
        #pragma unroll
        for (int r = 0; r < 4; r++) {
            const int grow = m0 + khalf * 4 + r;
            const int objc = objs[grow];
            float xv[2] = { acc0[r], acc1[r] };
            #pragma unroll
            for (int nf = 0; nf < 2; nf++) {
                const int col = bn + nf * 16 + r16;
                float x  = xv[nf];
                float e  = __expf(-fabsf(x));
                float t1 = 1.0f + e;
                float rc = __builtin_amdgcn_rcpf(t1);
                float sig = (x >= 0.0f) ? rc : e * rc;
                float sp = __logf(t1);
                float s  = (col == objc) ? x : -x;
                psum += fminf(s, 0.0f) - sp;
                outScore[(size_t)grow * NN + col] = sig;
            }
        }
    }
    red[tid] = psum;
    __syncthreads();
    for (int s = 128; s > 0; s >>= 1) {
        if (tid < s) red[tid] += red[tid + s];
        __syncthreads();
    }
    if (tid == 0) atomicAdd(accPath, (double)red[0]);
}

// ---------------------------------------------------------------------------
__global__ __launch_bounds__(256) void masked_softmax_all_kernel(
    const float* __restrict__ base, const float* __restrict__ part,
    unsigned short* __restrict__ aout_hi)
{
    __shared__ float sv[RR];
    __shared__ float red[256];
    const int blk = blockIdx.x;
    const int b = blk & (BB - 1);
    const int t = blk >> 10;
    const int tid = threadIdx.x;
    const float* brow = base + (size_t)b * RR;
    const float* prow = part + (size_t)b * (TT * RR) + t * RR;

    float lmax = -3.0e38f;
    for (int r = tid; r < RR; r += 256) {
        float v = prow[r] * brow[r];
        if (v == 0.0f) v = -1000000000.0f;
        sv[r] = v;
        lmax = fmaxf(lmax, v);
    }
    red[tid] = lmax;
    __syncthreads();
    for (int s = 128; s > 0; s >>= 1) {
        if (tid < s) red[tid] = fmaxf(red[tid], red[tid + s]);
        __syncthreads();
    }
    float gmax = red[0];
    __syncthreads();

    float lsum = 0.0f;
    for (int r = tid; r < RR; r += 256) {
        float e = __expf(sv[r] - gmax);
        sv[r] = e;
        lsum += e;
    }
    red[tid] = lsum;
    __syncthreads();
    for (int s = 128; s > 0; s >>= 1) {
        if (tid < s) red[tid] += red[tid + s];
        __syncthreads();
    }
    float inv = 1.0f / red[0];
    for (int r = tid; r < RR; r += 256)
        aout_hi[(size_t)blk * RR + r] = f2bf(sv[r] * inv);
}

__global__ void final_kernel(const double* __restrict__ acc, float* __restrict__ out)
{
    if (threadIdx.x == 0) {
        out[0] = (float)(acc[0] / ((double)BB * EE));
        out[1] = (float)(-acc[1] / ((double)BB * NN));
    }
}

// ---------------------------------------------------------------------------
extern "C" void kernel_launch(void* const* d_in, const int* in_sizes, int n_in,
                              void* d_out, int out_size, void* d_ws, size_t ws_size,
                              hipStream_t stream) {
    const float* pre_emb = (const float*)d_in[0];
    const float* r_emb   = (const float*)d_in[1];
    const float* part    = (const float*)d_in[2];
    const int*   triples = (const int*)d_in[3];
    const float* W1  = (const float*)d_in[6];
    const float* b1  = (const float*)d_in[7];
    const float* W2  = (const float*)d_in[8];
    const float* b2  = (const float*)d_in[9];
    const float* Wa  = (const float*)d_in[10];
    const float* ba  = (const float*)d_in[11];
    const float* Wh1 = (const float*)d_in[12];
    const float* bh1 = (const float*)d_in[13];
    const float* Wh2 = (const float*)d_in[14];
    const float* bh2 = (const float*)d_in[15];
    const float* Wal = (const float*)d_in[16];
    const float* bal = (const float*)d_in[17];
    const float* wih = (const float*)d_in[18];
    const float* whh = (const float*)d_in[19];
    const float* bih = (const float*)d_in[20];
    const float* bhh = (const float*)d_in[21];

    float* out = (float*)d_out;
    double* acc = (double*)d_ws;
    float* wsf = (float*)d_ws;
    size_t off = 4;
    auto alloc = [&](size_t n) { float* p = wsf + off; off += (n + 3) & ~(size_t)3; return p; };
    auto allocS = [&](size_t n) { return (unsigned short*)alloc((n + 1) / 2); };

    PrepPtrs p;
    p.W1h  = allocS((size_t)448 * 224);
    p.W1l  = allocS((size_t)448 * 224);
    p.W2h  = allocS((size_t)256 * 416);
    p.W2l  = allocS((size_t)256 * 416);
    p.Wabh = allocS((size_t)448 * 224);
    p.Wabl = allocS((size_t)448 * 224);
    p.Wh2h = allocS((size_t)256 * 224);
    p.Wh2l = allocS((size_t)256 * 224);
    p.Walh = allocS((size_t)256 * 224);
    p.Wall = allocS((size_t)256 * 224);
    p.WTh  = allocS((size_t)256 * 224);
    p.WTl  = allocS((size_t)256 * 224);
    p.wgh  = allocS((size_t)GP * KP);
    p.wgl  = allocS((size_t)GP * KP);
    p.whg  = allocS((size_t)GP * KP);
    p.whl  = allocS((size_t)GP * KP);
    p.bab  = alloc(448);
    p.bihp = alloc(GPR);
    p.bhhp = alloc(GP);
    p.mapSh = allocS((size_t)512 * 224);
    p.mapSl = allocS((size_t)512 * 224);
    p.wgiSh = allocS((size_t)GPR * RR);
    p.wgiSl = allocS((size_t)GPR * RR);
    p.hbufs = allocS((size_t)4 * BB * KP);
    p.acc = acc;

    unsigned short* ha_hi = p.hbufs;
    unsigned short* ha_lo = p.hbufs + (size_t)BB * KP;
    unsigned short* hb_hi = p.hbufs + (size_t)2 * BB * KP;
    unsigned short* hb_lo = p.hbufs + (size_t)3 * BB * KP;

    float* h1     = alloc((size_t)RR * 400);
    float* map    = alloc((size_t)RR * EE);
    float* qa_ph1 = alloc((size_t)BB * 448);
    float* basep  = alloc((size_t)BB * RR);
    unsigned short* aw_hi = allocS((size_t)TT * BB * RR);
    float* gi_all = alloc((size_t)TT * BB * GP);
    float* hfin   = alloc((size_t)BB * EE);
    float* pred   = alloc((size_t)BB * EE);
    float* ghid2  = alloc((size_t)BB * EE);
    float* s1h    = alloc((size_t)BB * EE);
    unsigned short* u_bf = allocS((size_t)BB * KP);

    dim3 blk(256);

    // 1. all prep in one launch
    prep_kernel<<<1024, blk, 0, stream>>>(
        W1, W2, Wa, Wh1, Wh2, Wal, bal, wih, whh, ba, bh1, bih, bhh, p);

    // 2. h1 = r_emb @ W1^T + b1   (480 x 400, K=200)
    mfma_flyA<0,0,0,0,0><<<dim3(7, 8), blk, 0, stream>>>(
        r_emb, 200, nullptr, 0, p.W1h, p.W1l, b1, h1, nullptr, nullptr,
        RR, 400, 200, 224, nullptr, 0, 0.f, 0);
    // 3. map = h1 @ W2^T + b2     (480 x 200, K=400) + hi/lo split
    mfma_flyA<0,3,0,0,0><<<dim3(4, 8), blk, 0, stream>>>(
        h1, 400, nullptr, 0, p.W2h, p.W2l, b2, map, p.mapSh, p.mapSl,
        RR, EE, 400, 416, nullptr, 0, 0.f, 224);
    // 4. qa_ph1 = map[rel] @ [Wa ; Wh1]^T + [ba ; bh1]  (1024 x 448)
    mfma_flyA<0,0,1,0,0><<<dim3(7, 16), blk, 0, stream>>>(
        map, 200, triples, 1, p.Wabh, p.Wabl, p.bab, qa_ph1, nullptr, nullptr,
        BB, 448, 200, 224, nullptr, 0, 0.f, 0);
    // 5. basep = qa @ map^T       (1024 x 480)
    mfma_flyA<0,0,0,0,0><<<dim3(8, 16), blk, 0, stream>>>(
        qa_ph1, 448, nullptr, 0, p.mapSh, p.mapSl, nullptr, basep, nullptr, nullptr,
        BB, RR, 200, 224, nullptr, 0, 0.f, 0);
    // 6. all-t masked softmax -> bf16 (hi only)
    masked_softmax_all_kernel<<<TT * BB, blk, 0, stream>>>(basep, part, aw_hi);
    // 7. Wgi = wih @ map^T  (600 x 480) -> gate-padded hi/lo
    mfma_flyA<0,2,0,1,0><<<dim3(8, 10), blk, 0, stream>>>(
        wih, 200, nullptr, 0, p.mapSh, p.mapSl, nullptr, nullptr, p.wgiSh, p.wgiSl,
        600, RR, 200, 224, nullptr, 0, 0.f, RR);
    // 8. gi_all = aw_all @ Wgi^T + bih  (8192 x 672, Ks=480) bf16x1
    mfma_linear1_kernel<<<dim3(11, TT * BB / 64), blk, 0, stream>>>(
        aw_hi, p.wgiSh, p.bihp, gi_all, TT * BB, GP, RR);

    // 9-16. GRU scan: 8 wide fused launches, t=0 skips the h-GEMM (h0 = 0).
    for (int t = 0; t < TT; t++) {
        const float* gi_t = gi_all + (size_t)t * BB * GP;
        const unsigned short* ih = (t & 1) ? hb_hi : ha_hi;
        const unsigned short* il = (t & 1) ? hb_lo : ha_lo;
        unsigned short* oh = (t & 1) ? ha_hi : hb_hi;
        unsigned short* ol = (t & 1) ? ha_lo : hb_lo;
        if (t == 0)
            gru_step_kernel<1,0><<<dim3(13, BB / 64), blk, 0, stream>>>(
                p.whg, p.whl, p.bhhp, gi_t, ih, il, oh, ol, nullptr);
        else if (t == TT - 1)
            gru_step_kernel<0,1><<<dim3(13, BB / 64), blk, 0, stream>>>(
                p.whg, p.whl, p.bhhp, gi_t, ih, il, oh, ol, hfin);
        else
            gru_step_kernel<0,0><<<dim3(13, BB / 64), blk, 0, stream>>>(
                p.whg, p.whl, p.bhhp, gi_t, ih, il, oh, ol, nullptr);
    }

    // 17. pred = 0.1*(ph1 @ Wh2^T + bh2) + map[rel]
    mfma_flyA<1,0,0,0,1><<<dim3(4, 16), blk, 0, stream>>>(
        qa_ph1 + 224, 448, triples, 1, p.Wh2h, p.Wh2l, bh2, pred, nullptr, nullptr,
        BB, EE, 200, 224, map, 200, 0.1f, 0);
    // 18. gru_hidden2 fused + match-loss partial
    gru2_fused_kernel<<<dim3(13, BB / 64), blk, 0, stream>>>(
        p.wgh, p.wgl, p.whg, p.whl, p.bihp, p.bhhp,
        triples, map, pred, hfin, ghid2, acc + 0);
    // 19. s1h = (pre_emb[sub] @ Wal^T + bal) * ghid2
    mfma_flyA<2,0,1,0,0><<<dim3(4, 16), blk, 0, stream>>>(
        pre_emb, 200, triples, 0, p.Walh, p.Wall, bal, s1h, nullptr, nullptr,
        BB, EE, 200, 224, ghid2, 200, 0.f, 0);
    // 20. u = s1h @ [Wal^T ; bal] -> bf16 [1024][224]
    mfma_flyA<0,1,0,0,0><<<dim3(4, 16), blk, 0, stream>>>(
        s1h, 200, nullptr, 0, p.WTh, p.WTl, nullptr, nullptr, u_bf, nullptr,
        BB, KP, 200, 224, nullptr, 0, 0.f, KP);
    // 21. score + path loss (32-col stripes, 1250 blocks)
    score_mfma2_kernel<<<NN / 32, blk, 0, stream>>>(u_bf, pre_emb, triples, out + 2, acc + 1);
    // 22. finalize
    final_kernel<<<1, 64, 0, stream>>>(acc, out);
}